// Round 1
// baseline (499.842 us; speedup 1.0000x reference)
//
#include <hip/hip_runtime.h>
#include <math.h>

// Problem constants (fixed by setup_inputs)
#define BTOT 1024
#define NE   16
#define NA   4
#define DD   48        // NE*3
#define HH   512
#define ROWS (BTOT * DD)   // 49152

// ---------------------------------------------------------------------------
// K0: transpose W2 -> W2T (so the u-matvec reads coalesced columns)
// ---------------------------------------------------------------------------
__global__ __launch_bounds__(256) void k_transpose(const float* __restrict__ W2,
                                                   float* __restrict__ W2T) {
  __shared__ float tile[32][33];
  int bx = blockIdx.x * 32, by = blockIdx.y * 32;
  int tx = threadIdx.x, ty = threadIdx.y;  // (32, 8)
  for (int r = 0; r < 32; r += 8)
    tile[ty + r][tx] = W2[(by + ty + r) * HH + bx + tx];
  __syncthreads();
  for (int r = 0; r < 32; r += 8)
    W2T[(bx + ty + r) * HH + by + tx] = tile[tx][ty + r];
}

// ---------------------------------------------------------------------------
// K1: per-sample forward + backward (everything except the m-GEMM term)
//   outputs: D1[b][j], C2[b][k], HD1[b][i], GSQ[b], POT[b]
// ---------------------------------------------------------------------------
__global__ __launch_bounds__(256) void k_persample(
    const float* __restrict__ X, const float* __restrict__ ATOM,
    const float* __restrict__ Z, const float* __restrict__ W1,
    const float* __restrict__ B1, const float* __restrict__ W2,
    const float* __restrict__ B2, const float* __restrict__ w3,
    const float* __restrict__ W2T,
    float* __restrict__ D1, float* __restrict__ C2,
    float* __restrict__ HD1, float* __restrict__ GSQ, float* __restrict__ POT) {
  const int b = blockIdx.x, tid = threadIdx.x;
  __shared__ float xs[DD];
  __shared__ float t1s[HH], d1s[HH], vs[HH], s1s[HH], c1s[HH];
  __shared__ float gtmp[DD];
  __shared__ float red[256];

  if (tid < DD) xs[tid] = X[b * DD + tid];
  __syncthreads();

  // ---- layer 1: a1 = x@W1 + b1 ; two j per thread
  {
    const int j0 = tid * 2;
    float acc0 = B1[j0], acc1 = B1[j0 + 1];
#pragma unroll 8
    for (int i = 0; i < DD; ++i) {
      float xv = xs[i];
      float2 w = *reinterpret_cast<const float2*>(&W1[i * HH + j0]);
      acc0 = fmaf(xv, w.x, acc0);
      acc1 = fmaf(xv, w.y, acc1);
    }
    float t0 = tanhf(acc0), t1v = tanhf(acc1);
    t1s[j0] = t0; t1s[j0 + 1] = t1v;
    float dd0 = 1.f - t0 * t0, dd1 = 1.f - t1v * t1v;
    d1s[j0] = dd0; d1s[j0 + 1] = dd1;
    *reinterpret_cast<float2*>(&D1[b * HH + j0]) = make_float2(dd0, dd1);
  }
  __syncthreads();

  // ---- layer 2: a2 = t1@W2 + b2 ; v = w3*d2 ; c2 = -2*t2*d2*w3
  {
    const int k0 = tid * 2;
    float acc0 = B2[k0], acc1 = B2[k0 + 1];
#pragma unroll 4
    for (int j = 0; j < HH; ++j) {
      float tv = t1s[j];
      float2 w = *reinterpret_cast<const float2*>(&W2[j * HH + k0]);
      acc0 = fmaf(tv, w.x, acc0);
      acc1 = fmaf(tv, w.y, acc1);
    }
    float t20 = tanhf(acc0), t21 = tanhf(acc1);
    float d20 = 1.f - t20 * t20, d21 = 1.f - t21 * t21;
    float w30 = w3[k0], w31 = w3[k0 + 1];
    vs[k0] = w30 * d20; vs[k0 + 1] = w31 * d21;
    float c20 = -2.f * t20 * d20 * w30, c21 = -2.f * t21 * d21 * w31;
    *reinterpret_cast<float2*>(&C2[b * HH + k0]) = make_float2(c20, c21);
  }
  __syncthreads();

  // ---- u_j = sum_k W2[j,k] v_k = sum_k W2T[k,j] v_k ; s1 = d1*u ; c1 = -2*t1*d1*u
  {
    const int j0 = tid * 2;
    float acc0 = 0.f, acc1 = 0.f;
#pragma unroll 4
    for (int k = 0; k < HH; ++k) {
      float vv = vs[k];
      float2 w = *reinterpret_cast<const float2*>(&W2T[k * HH + j0]);
      acc0 = fmaf(vv, w.x, acc0);
      acc1 = fmaf(vv, w.y, acc1);
    }
    float t10 = t1s[j0], t11 = t1s[j0 + 1];
    float dd0 = d1s[j0], dd1 = d1s[j0 + 1];
    s1s[j0] = dd0 * acc0;      s1s[j0 + 1] = dd1 * acc1;
    c1s[j0] = -2.f * t10 * dd0 * acc0;
    c1s[j0 + 1] = -2.f * t11 * dd1 * acc1;
  }
  __syncthreads();

  // ---- g_i = sum_j W1[i,j] s1_j ; hd1_i = sum_j W1[i,j]^2 c1_j
  {
    const int wid = tid >> 6, lane = tid & 63;
    for (int i = wid; i < DD; i += 4) {
      float gp = 0.f, hp = 0.f;
      for (int j = lane; j < HH; j += 64) {
        float w = W1[i * HH + j];
        gp = fmaf(w, s1s[j], gp);
        hp = fmaf(w * w, c1s[j], hp);
      }
#pragma unroll
      for (int off = 32; off > 0; off >>= 1) {
        gp += __shfl_down(gp, off);
        hp += __shfl_down(hp, off);
      }
      if (lane == 0) { gtmp[i] = gp; HD1[b * DD + i] = hp; }
    }
  }
  __syncthreads();

  // ---- gsq
  if (tid < 64) {
    float v = (tid < DD) ? gtmp[tid] : 0.f;
    float sq = v * v;
#pragma unroll
    for (int off = 32; off > 0; off >>= 1) sq += __shfl_down(sq, off);
    if (tid == 0) GSQ[b] = sq;
  }

  // ---- potential (deterministic tree reduction)
  {
    float p = 0.f;
    // electron-electron, i<j pairs
    for (int pr = tid; pr < NE * (NE - 1) / 2; pr += 256) {
      int i = 0, rem = pr;
      while (rem >= NE - 1 - i) { rem -= NE - 1 - i; ++i; }
      int j = i + 1 + rem;
      float dx = xs[i * 3 + 0] - xs[j * 3 + 0];
      float dy = xs[i * 3 + 1] - xs[j * 3 + 1];
      float dz = xs[i * 3 + 2] - xs[j * 3 + 2];
      float r = fmaxf(sqrtf(dx * dx + dy * dy + dz * dz), 1e-10f);
      p += 1.f / r;
    }
    // electron-nucleus
    for (int idx = tid; idx < NE * NA; idx += 256) {
      int e = idx / NA, a = idx % NA;
      float dx = xs[e * 3 + 0] - ATOM[a * 3 + 0];
      float dy = xs[e * 3 + 1] - ATOM[a * 3 + 1];
      float dz = xs[e * 3 + 2] - ATOM[a * 3 + 2];
      float r = fmaxf(sqrtf(dx * dx + dy * dy + dz * dz), 1e-10f);
      p -= Z[a] / r;
    }
    // nucleus-nucleus (thread 0)
    if (tid == 0) {
      for (int a = 0; a < NA; ++a)
        for (int a2 = a + 1; a2 < NA; ++a2) {
          float dx = ATOM[a * 3 + 0] - ATOM[a2 * 3 + 0];
          float dy = ATOM[a * 3 + 1] - ATOM[a2 * 3 + 1];
          float dz = ATOM[a * 3 + 2] - ATOM[a2 * 3 + 2];
          float r = sqrtf(dx * dx + dy * dy + dz * dz);
          if (r > 1e-10f) p += Z[a] * Z[a2] / r;
        }
    }
    red[tid] = p;
    __syncthreads();
    for (int s = 128; s > 0; s >>= 1) {
      if (tid < s) red[tid] += red[tid + s];
      __syncthreads();
    }
    if (tid == 0) POT[b] = fminf(fmaxf(red[0], -1000.f), 1000.f);
  }
}

// ---------------------------------------------------------------------------
// K2: Mbig[49152,512] = Abig @ W2, Abig[b*48+i][j] = W1[i,j]*D1[b,j],
//     fused epilogue: HD2P[cb][row] = sum_{k in col-block} C2[b,k]*m^2
//     (classic 64x64x16 fp32 tile, 4x4 per thread; MFMA comes next round)
// ---------------------------------------------------------------------------
#define BM 64
#define BN 64
#define BK 16

__global__ __launch_bounds__(256) void k_mgemm(
    const float* __restrict__ W1, const float* __restrict__ W2,
    const float* __restrict__ D1, const float* __restrict__ C2,
    float* __restrict__ HD2P) {
  const int cb = blockIdx.x;   // 0..7  column block
  const int rb = blockIdx.y;   // 0..767 row block
  const int tid = threadIdx.x;
  const int tx = tid & 15;     // col group (4 cols each)
  const int ty = tid >> 4;     // row group (4 rows each)
  const int row0 = rb * BM;
  const int col0 = cb * BN;

  __shared__ float As[BK][BM + 4];  // +4 pad: keeps float4 alignment, breaks bank collisions
  __shared__ float Bs[BK][BN];

  float acc[4][4] = {};

  // A staging: thread loads 4 consecutive j of one row per k-tile
  const int arow = tid >> 2;
  const int aj4 = (tid & 3) * 4;
  const int grow = row0 + arow;
  const float* w1row = &W1[(grow % DD) * HH];
  const float* d1row = &D1[(grow / DD) * HH];
  // B staging
  const int bj = tid >> 4;
  const int bn4 = (tid & 15) * 4;

  for (int kt = 0; kt < HH; kt += BK) {
    float4 wv = *reinterpret_cast<const float4*>(&w1row[kt + aj4]);
    float4 dv = *reinterpret_cast<const float4*>(&d1row[kt + aj4]);
    As[aj4 + 0][arow] = wv.x * dv.x;
    As[aj4 + 1][arow] = wv.y * dv.y;
    As[aj4 + 2][arow] = wv.z * dv.z;
    As[aj4 + 3][arow] = wv.w * dv.w;
    *reinterpret_cast<float4*>(&Bs[bj][bn4]) =
        *reinterpret_cast<const float4*>(&W2[(kt + bj) * HH + col0 + bn4]);
    __syncthreads();
#pragma unroll
    for (int kk = 0; kk < BK; ++kk) {
      float4 av = *reinterpret_cast<const float4*>(&As[kk][ty * 4]);
      float4 bv = *reinterpret_cast<const float4*>(&Bs[kk][tx * 4]);
      float a[4] = {av.x, av.y, av.z, av.w};
      float bb[4] = {bv.x, bv.y, bv.z, bv.w};
#pragma unroll
      for (int e = 0; e < 4; ++e)
#pragma unroll
        for (int f = 0; f < 4; ++f)
          acc[e][f] = fmaf(a[e], bb[f], acc[e][f]);
    }
    __syncthreads();
  }

  // epilogue: weighted square-sum over this block's 64 columns, deterministic
#pragma unroll
  for (int e = 0; e < 4; ++e) {
    const int r = row0 + ty * 4 + e;
    const int bsm = r / DD;
    const float* c2row = &C2[bsm * HH + col0];
    float s = 0.f;
#pragma unroll
    for (int f = 0; f < 4; ++f) {
      float m = acc[e][f];
      s = fmaf(c2row[tx * 4 + f] * m, m, s);
    }
    // reduce across the 16 tx threads sharing this row (width-16 subgroups)
#pragma unroll
    for (int off = 8; off > 0; off >>= 1) s += __shfl_down(s, off, 16);
    if (tx == 0) HD2P[cb * ROWS + r] = s;
  }
}

// ---------------------------------------------------------------------------
// K3: finalize: out[b] = clip(-0.5*(lap+gsq), +-100) + pot
// ---------------------------------------------------------------------------
__global__ void k_finalize(const float* __restrict__ HD1,
                           const float* __restrict__ HD2P,
                           const float* __restrict__ GSQ,
                           const float* __restrict__ POT,
                           float* __restrict__ OUT) {
  int b = blockIdx.x * blockDim.x + threadIdx.x;
  if (b >= BTOT) return;
  float lap = 0.f;
  for (int i = 0; i < DD; ++i) {
    float h = HD1[b * DD + i];
#pragma unroll
    for (int c = 0; c < 8; ++c) h += HD2P[c * ROWS + b * DD + i];
    // reference: where(isfinite, clip(h, -50, 50), 0)
    if (h >= -1e30f && h <= 1e30f) h = fminf(fmaxf(h, -50.f), 50.f);
    else h = 0.f;
    lap += h;
  }
  float kin = fminf(fmaxf(-0.5f * (lap + GSQ[b]), -100.f), 100.f);
  OUT[b] = kin + POT[b];
}

// ---------------------------------------------------------------------------
extern "C" void kernel_launch(void* const* d_in, const int* in_sizes, int n_in,
                              void* d_out, int out_size, void* d_ws, size_t ws_size,
                              hipStream_t stream) {
  const float* X    = (const float*)d_in[0];  // [1024,16,3]
  const float* ATOM = (const float*)d_in[1];  // [4,3]
  const float* Z    = (const float*)d_in[2];  // [4]
  const float* W1   = (const float*)d_in[3];  // [48,512]
  const float* B1   = (const float*)d_in[4];  // [512]
  const float* W2   = (const float*)d_in[5];  // [512,512]
  const float* B2   = (const float*)d_in[6];  // [512]
  const float* w3   = (const float*)d_in[7];  // [512]
  float* out = (float*)d_out;

  float* ws = (float*)d_ws;
  float* W2T  = ws;                    // 512*512          = 262144
  float* D1   = W2T + HH * HH;         // 1024*512         = 524288
  float* C2   = D1 + BTOT * HH;        // 1024*512         = 524288
  float* HD1  = C2 + BTOT * HH;        // 49152
  float* GSQ  = HD1 + ROWS;            // 1024
  float* POT  = GSQ + BTOT;            // 1024
  float* HD2P = POT + BTOT;            // 8*49152 = 393216   (total ~7 MB)

  k_transpose<<<dim3(16, 16), dim3(32, 8), 0, stream>>>(W2, W2T);
  k_persample<<<BTOT, 256, 0, stream>>>(X, ATOM, Z, W1, B1, W2, B2, w3, W2T,
                                        D1, C2, HD1, GSQ, POT);
  k_mgemm<<<dim3(8, ROWS / BM), 256, 0, stream>>>(W1, W2, D1, C2, HD2P);
  k_finalize<<<(BTOT + 255) / 256, 256, 0, stream>>>(HD1, HD2P, GSQ, POT, out);
}

// Round 2
// 245.648 us; speedup vs baseline: 2.0348x; 2.0348x over previous
//
#include <hip/hip_runtime.h>
#include <math.h>

// Problem constants (fixed by setup_inputs)
#define BTOT 1024
#define NE   16
#define NA   4
#define DD   48        // NE*3
#define HH   512
#define ROWS (BTOT * DD)   // 49152

// GEMM tile (K2)
#define GBM 128
#define GBN 128
#define GBK 64
#define NCB (HH / GBN)   // 4 column blocks

typedef __attribute__((ext_vector_type(8))) short bf16x8;          // 8 bf16 (4 VGPRs)
typedef __attribute__((ext_vector_type(8))) unsigned short u16x8;
typedef __attribute__((ext_vector_type(4))) float f32x4;

__device__ inline unsigned short f2bf(float f) {
  unsigned int u = __builtin_bit_cast(unsigned int, f);
  u += 0x7fffu + ((u >> 16) & 1u);   // round-to-nearest-even
  return (unsigned short)(u >> 16);
}

// ushort index of 16B chunk `chunk` of row `row` in a [*][64]-bf16 LDS tile,
// XOR-swizzled so stride-128B column reads spread across 8 bank slots (T2).
__device__ inline int swz(int row, int chunk) {
  return (row << 6) + ((chunk ^ (row & 7)) << 3);
}

// ---------------------------------------------------------------------------
// K0: transpose W2 -> W2T (fp32, for k_persample's u-matvec) and W2Tb (bf16,
//     B-operand of the MFMA GEMM: row-major [col][k])
// ---------------------------------------------------------------------------
__global__ __launch_bounds__(256) void k_transpose(const float* __restrict__ W2,
                                                   float* __restrict__ W2T,
                                                   ushort* __restrict__ W2Tb) {
  __shared__ float tile[32][33];
  int bx = blockIdx.x * 32, by = blockIdx.y * 32;
  int tx = threadIdx.x, ty = threadIdx.y;  // (32, 8)
  for (int r = 0; r < 32; r += 8)
    tile[ty + r][tx] = W2[(by + ty + r) * HH + bx + tx];
  __syncthreads();
  for (int r = 0; r < 32; r += 8) {
    float v = tile[tx][ty + r];
    W2T[(bx + ty + r) * HH + by + tx] = v;
    W2Tb[(bx + ty + r) * HH + by + tx] = f2bf(v);
  }
}

// ---------------------------------------------------------------------------
// K1: per-sample forward + backward (everything except the m-GEMM term)
//   outputs: D1[b][j], C2[b][k], HD1[b][i], GSQ[b], POT[b]
// ---------------------------------------------------------------------------
__global__ __launch_bounds__(256) void k_persample(
    const float* __restrict__ X, const float* __restrict__ ATOM,
    const float* __restrict__ Z, const float* __restrict__ W1,
    const float* __restrict__ B1, const float* __restrict__ W2,
    const float* __restrict__ B2, const float* __restrict__ w3,
    const float* __restrict__ W2T,
    float* __restrict__ D1, float* __restrict__ C2,
    float* __restrict__ HD1, float* __restrict__ GSQ, float* __restrict__ POT) {
  const int b = blockIdx.x, tid = threadIdx.x;
  __shared__ float xs[DD];
  __shared__ float t1s[HH], d1s[HH], vs[HH], s1s[HH], c1s[HH];
  __shared__ float gtmp[DD];
  __shared__ float red[256];

  if (tid < DD) xs[tid] = X[b * DD + tid];
  __syncthreads();

  // ---- layer 1: a1 = x@W1 + b1 ; two j per thread
  {
    const int j0 = tid * 2;
    float acc0 = B1[j0], acc1 = B1[j0 + 1];
#pragma unroll 8
    for (int i = 0; i < DD; ++i) {
      float xv = xs[i];
      float2 w = *reinterpret_cast<const float2*>(&W1[i * HH + j0]);
      acc0 = fmaf(xv, w.x, acc0);
      acc1 = fmaf(xv, w.y, acc1);
    }
    float t0 = tanhf(acc0), t1v = tanhf(acc1);
    t1s[j0] = t0; t1s[j0 + 1] = t1v;
    float dd0 = 1.f - t0 * t0, dd1 = 1.f - t1v * t1v;
    d1s[j0] = dd0; d1s[j0 + 1] = dd1;
    *reinterpret_cast<float2*>(&D1[b * HH + j0]) = make_float2(dd0, dd1);
  }
  __syncthreads();

  // ---- layer 2: a2 = t1@W2 + b2 ; v = w3*d2 ; c2 = -2*t2*d2*w3
  {
    const int k0 = tid * 2;
    float acc0 = B2[k0], acc1 = B2[k0 + 1];
#pragma unroll 4
    for (int j = 0; j < HH; ++j) {
      float tv = t1s[j];
      float2 w = *reinterpret_cast<const float2*>(&W2[j * HH + k0]);
      acc0 = fmaf(tv, w.x, acc0);
      acc1 = fmaf(tv, w.y, acc1);
    }
    float t20 = tanhf(acc0), t21 = tanhf(acc1);
    float d20 = 1.f - t20 * t20, d21 = 1.f - t21 * t21;
    float w30 = w3[k0], w31 = w3[k0 + 1];
    vs[k0] = w30 * d20; vs[k0 + 1] = w31 * d21;
    float c20 = -2.f * t20 * d20 * w30, c21 = -2.f * t21 * d21 * w31;
    *reinterpret_cast<float2*>(&C2[b * HH + k0]) = make_float2(c20, c21);
  }
  __syncthreads();

  // ---- u_j = sum_k W2T[k,j] v_k ; s1 = d1*u ; c1 = -2*t1*d1*u
  {
    const int j0 = tid * 2;
    float acc0 = 0.f, acc1 = 0.f;
#pragma unroll 4
    for (int k = 0; k < HH; ++k) {
      float vv = vs[k];
      float2 w = *reinterpret_cast<const float2*>(&W2T[k * HH + j0]);
      acc0 = fmaf(vv, w.x, acc0);
      acc1 = fmaf(vv, w.y, acc1);
    }
    float t10 = t1s[j0], t11 = t1s[j0 + 1];
    float dd0 = d1s[j0], dd1 = d1s[j0 + 1];
    s1s[j0] = dd0 * acc0;      s1s[j0 + 1] = dd1 * acc1;
    c1s[j0] = -2.f * t10 * dd0 * acc0;
    c1s[j0 + 1] = -2.f * t11 * dd1 * acc1;
  }
  __syncthreads();

  // ---- g_i = sum_j W1[i,j] s1_j ; hd1_i = sum_j W1[i,j]^2 c1_j
  {
    const int wid = tid >> 6, lane = tid & 63;
    for (int i = wid; i < DD; i += 4) {
      float gp = 0.f, hp = 0.f;
      for (int j = lane; j < HH; j += 64) {
        float w = W1[i * HH + j];
        gp = fmaf(w, s1s[j], gp);
        hp = fmaf(w * w, c1s[j], hp);
      }
#pragma unroll
      for (int off = 32; off > 0; off >>= 1) {
        gp += __shfl_down(gp, off);
        hp += __shfl_down(hp, off);
      }
      if (lane == 0) { gtmp[i] = gp; HD1[b * DD + i] = hp; }
    }
  }
  __syncthreads();

  // ---- gsq
  if (tid < 64) {
    float v = (tid < DD) ? gtmp[tid] : 0.f;
    float sq = v * v;
#pragma unroll
    for (int off = 32; off > 0; off >>= 1) sq += __shfl_down(sq, off);
    if (tid == 0) GSQ[b] = sq;
  }

  // ---- potential (deterministic tree reduction)
  {
    float p = 0.f;
    for (int pr = tid; pr < NE * (NE - 1) / 2; pr += 256) {
      int i = 0, rem = pr;
      while (rem >= NE - 1 - i) { rem -= NE - 1 - i; ++i; }
      int j = i + 1 + rem;
      float dx = xs[i * 3 + 0] - xs[j * 3 + 0];
      float dy = xs[i * 3 + 1] - xs[j * 3 + 1];
      float dz = xs[i * 3 + 2] - xs[j * 3 + 2];
      float r = fmaxf(sqrtf(dx * dx + dy * dy + dz * dz), 1e-10f);
      p += 1.f / r;
    }
    for (int idx = tid; idx < NE * NA; idx += 256) {
      int e = idx / NA, a = idx % NA;
      float dx = xs[e * 3 + 0] - ATOM[a * 3 + 0];
      float dy = xs[e * 3 + 1] - ATOM[a * 3 + 1];
      float dz = xs[e * 3 + 2] - ATOM[a * 3 + 2];
      float r = fmaxf(sqrtf(dx * dx + dy * dy + dz * dz), 1e-10f);
      p -= Z[a] / r;
    }
    if (tid == 0) {
      for (int a = 0; a < NA; ++a)
        for (int a2 = a + 1; a2 < NA; ++a2) {
          float dx = ATOM[a * 3 + 0] - ATOM[a2 * 3 + 0];
          float dy = ATOM[a * 3 + 1] - ATOM[a2 * 3 + 1];
          float dz = ATOM[a * 3 + 2] - ATOM[a2 * 3 + 2];
          float r = sqrtf(dx * dx + dy * dy + dz * dz);
          if (r > 1e-10f) p += Z[a] * Z[a2] / r;
        }
    }
    red[tid] = p;
    __syncthreads();
    for (int s = 128; s > 0; s >>= 1) {
      if (tid < s) red[tid] += red[tid + s];
      __syncthreads();
    }
    if (tid == 0) POT[b] = fminf(fmaxf(red[0], -1000.f), 1000.f);
  }
}

// ---------------------------------------------------------------------------
// K2 (MFMA): Mbig[49152,512] = Abig @ W2, Abig[b*48+i][j] = W1[i,j]*D1[b,j]
//   bf16 MFMA 16x16x32, 128x128 tile, BK=64, 4 waves x (64x64), XOR-swizzled
//   LDS, fused epilogue HD2P[cb][row] = sum_{k in col-block} C2[b,k]*m^2.
//   Fragment layout (gfx950): A/B lane l elem e -> k=(l>>4)*8+e, row/col=l&15;
//   C/D: col=lane&15, row=(lane>>4)*4+reg.
// ---------------------------------------------------------------------------
__global__ __launch_bounds__(256) void k_mgemm_mfma(
    const float* __restrict__ W1, const ushort* __restrict__ W2Tb,
    const float* __restrict__ D1, const float* __restrict__ C2,
    float* __restrict__ HD2P) {
  const int cb = blockIdx.x;        // 0..3
  const int rb = blockIdx.y;        // 0..383
  const int row0 = rb * GBM;
  const int col0 = cb * GBN;
  const int t = threadIdx.x;

  __shared__ ushort As[GBM * GBK];  // 16 KB, row-major [row][k], swizzled chunks
  __shared__ ushort Bs[GBN * GBK];  // 16 KB, [col][k], swizzled chunks

  // staging: thread t owns row/col sr, k-half skh (32 wide)
  const int sr = t >> 1;
  const int skh = (t & 1) * 32;
  const int grow = row0 + sr;
  const int bsmp = grow / DD;
  const int rw = grow - bsmp * DD;
  const float* __restrict__ w1p = &W1[rw * HH];
  const float* __restrict__ d1p = &D1[bsmp * HH];
  const ushort* __restrict__ bp = &W2Tb[(col0 + sr) * HH];

  const int wave = t >> 6, lane = t & 63;
  const int wm = wave >> 1, wn = wave & 1;
  const int lr = lane & 15, lg = lane >> 4;

  f32x4 acc[4][4];
#pragma unroll
  for (int m = 0; m < 4; ++m)
#pragma unroll
    for (int n = 0; n < 4; ++n) acc[m][n] = (f32x4)0.f;

  for (int kt = 0; kt < HH; kt += GBK) {
    // ---- stage A (compute W1*D1 -> bf16) and B (copy bf16)
#pragma unroll
    for (int q = 0; q < 4; ++q) {
      const int k = kt + skh + q * 8;
      float4 wa = *reinterpret_cast<const float4*>(&w1p[k]);
      float4 wb = *reinterpret_cast<const float4*>(&w1p[k + 4]);
      float4 da = *reinterpret_cast<const float4*>(&d1p[k]);
      float4 db = *reinterpret_cast<const float4*>(&d1p[k + 4]);
      u16x8 pk;
      pk[0] = f2bf(wa.x * da.x); pk[1] = f2bf(wa.y * da.y);
      pk[2] = f2bf(wa.z * da.z); pk[3] = f2bf(wa.w * da.w);
      pk[4] = f2bf(wb.x * db.x); pk[5] = f2bf(wb.y * db.y);
      pk[6] = f2bf(wb.z * db.z); pk[7] = f2bf(wb.w * db.w);
      *reinterpret_cast<u16x8*>(&As[swz(sr, (skh >> 3) + q)]) = pk;
      *reinterpret_cast<u16x8*>(&Bs[swz(sr, (skh >> 3) + q)]) =
          *reinterpret_cast<const u16x8*>(&bp[k]);
    }
    __syncthreads();
    // ---- compute: 2 K-steps of 32, 16 MFMAs each
#pragma unroll
    for (int k0 = 0; k0 < GBK; k0 += 32) {
      const int ck = (k0 >> 3) + lg;
      bf16x8 af[4], bfr[4];
#pragma unroll
      for (int m = 0; m < 4; ++m)
        af[m] = *reinterpret_cast<const bf16x8*>(&As[swz(wm * 64 + m * 16 + lr, ck)]);
#pragma unroll
      for (int n = 0; n < 4; ++n)
        bfr[n] = *reinterpret_cast<const bf16x8*>(&Bs[swz(wn * 64 + n * 16 + lr, ck)]);
#pragma unroll
      for (int m = 0; m < 4; ++m)
#pragma unroll
        for (int n = 0; n < 4; ++n)
          acc[m][n] = __builtin_amdgcn_mfma_f32_16x16x32_bf16(af[m], bfr[n],
                                                              acc[m][n], 0, 0, 0);
    }
    __syncthreads();
  }

  // ---- fused epilogue: per-row weighted square-sum over this block's cols
#pragma unroll
  for (int m = 0; m < 4; ++m) {
#pragma unroll
    for (int e = 0; e < 4; ++e) {
      const int row_g = row0 + wm * 64 + m * 16 + lg * 4 + e;
      const int bs2 = row_g / DD;
      const float* __restrict__ c2p = &C2[bs2 * HH + col0 + wn * 64 + lr];
      float s = 0.f;
#pragma unroll
      for (int n = 0; n < 4; ++n) {
        float mv = acc[m][n][e];
        s = fmaf(c2p[n * 16] * mv, mv, s);
      }
      s += __shfl_xor(s, 1);
      s += __shfl_xor(s, 2);
      s += __shfl_xor(s, 4);
      s += __shfl_xor(s, 8);
      if (lr == 0) HD2P[cb * ROWS + row_g] = s;
    }
  }
}

// ---------------------------------------------------------------------------
// K3: finalize: out[b] = clip(-0.5*(lap+gsq), +-100) + pot
// ---------------------------------------------------------------------------
__global__ void k_finalize(const float* __restrict__ HD1,
                           const float* __restrict__ HD2P,
                           const float* __restrict__ GSQ,
                           const float* __restrict__ POT,
                           float* __restrict__ OUT) {
  int b = blockIdx.x * blockDim.x + threadIdx.x;
  if (b >= BTOT) return;
  float lap = 0.f;
  for (int i = 0; i < DD; ++i) {
    float h = HD1[b * DD + i];
#pragma unroll
    for (int c = 0; c < NCB; ++c) h += HD2P[c * ROWS + b * DD + i];
    if (h >= -1e30f && h <= 1e30f) h = fminf(fmaxf(h, -50.f), 50.f);
    else h = 0.f;
    lap += h;
  }
  float kin = fminf(fmaxf(-0.5f * (lap + GSQ[b]), -100.f), 100.f);
  OUT[b] = kin + POT[b];
}

// ---------------------------------------------------------------------------
extern "C" void kernel_launch(void* const* d_in, const int* in_sizes, int n_in,
                              void* d_out, int out_size, void* d_ws, size_t ws_size,
                              hipStream_t stream) {
  const float* X    = (const float*)d_in[0];  // [1024,16,3]
  const float* ATOM = (const float*)d_in[1];  // [4,3]
  const float* Z    = (const float*)d_in[2];  // [4]
  const float* W1   = (const float*)d_in[3];  // [48,512]
  const float* B1   = (const float*)d_in[4];  // [512]
  const float* W2   = (const float*)d_in[5];  // [512,512]
  const float* B2   = (const float*)d_in[6];  // [512]
  const float* w3   = (const float*)d_in[7];  // [512]
  float* out = (float*)d_out;

  float* ws = (float*)d_ws;
  float*  W2T  = ws;                         // 262144 floats
  ushort* W2Tb = (ushort*)(ws + 262144);     // 131072 float-slots
  float*  D1   = ws + 262144 + 131072;       // 524288
  float*  C2   = D1 + BTOT * HH;             // 524288
  float*  HD1  = C2 + BTOT * HH;             // 49152
  float*  GSQ  = HD1 + ROWS;                 // 1024
  float*  POT  = GSQ + BTOT;                 // 1024
  float*  HD2P = POT + BTOT;                 // 4*49152 (~6.8 MB total)

  k_transpose<<<dim3(16, 16), dim3(32, 8), 0, stream>>>(W2, W2T, W2Tb);
  k_persample<<<BTOT, 256, 0, stream>>>(X, ATOM, Z, W1, B1, W2, B2, w3, W2T,
                                        D1, C2, HD1, GSQ, POT);
  k_mgemm_mfma<<<dim3(NCB, ROWS / GBM), 256, 0, stream>>>(W1, W2Tb, D1, C2, HD2P);
  k_finalize<<<(BTOT + 255) / 256, 256, 0, stream>>>(HD1, HD2P, GSQ, POT, out);
}

// Round 3
// 173.441 us; speedup vs baseline: 2.8819x; 1.4163x over previous
//
#include <hip/hip_runtime.h>
#include <math.h>

// Problem constants (fixed by setup_inputs)
#define BTOT 1024
#define NE   16
#define NA   4
#define DD   48        // NE*3
#define HH   512
#define ROWS (BTOT * DD)   // 49152

// GEMM tile (shared by all MFMA kernels)
#define GBM 128
#define GBN 128
#define GBK 64
#define NCB (HH / GBN)   // 4 column blocks

typedef __attribute__((ext_vector_type(8))) short bf16x8;          // 8 bf16 (4 VGPRs)
typedef __attribute__((ext_vector_type(8))) unsigned short u16x8;
typedef __attribute__((ext_vector_type(4))) float f32x4;

__device__ inline unsigned short f2bf(float f) {
  unsigned int u = __builtin_bit_cast(unsigned int, f);
  u += 0x7fffu + ((u >> 16) & 1u);   // round-to-nearest-even
  return (unsigned short)(u >> 16);
}
__device__ inline float bf2f(unsigned short s) {
  unsigned int u = ((unsigned int)s) << 16;
  return __builtin_bit_cast(float, u);
}

// ushort index of 16B chunk `chunk` of row `row` in a [*][64]-bf16 LDS tile,
// XOR-swizzled so stride-128B column reads spread across 8 bank slots (T2).
__device__ inline int swz(int row, int chunk) {
  return (row << 6) + ((chunk ^ (row & 7)) << 3);
}

// ---------------------------------------------------------------------------
// K0: W2 -> W2b (bf16 row-major, B-operand for U-GEMM) and
//           W2Tb (bf16 transpose, B-operand for act-GEMM and m-GEMM)
// ---------------------------------------------------------------------------
__global__ __launch_bounds__(256) void k_prep(const float* __restrict__ W2,
                                              ushort* __restrict__ W2b,
                                              ushort* __restrict__ W2Tb) {
  __shared__ float tile[32][33];
  int bx = blockIdx.x * 32, by = blockIdx.y * 32;
  int tx = threadIdx.x, ty = threadIdx.y;  // (32, 8)
  for (int r = 0; r < 32; r += 8) {
    float v = W2[(by + ty + r) * HH + bx + tx];
    tile[ty + r][tx] = v;
    W2b[(by + ty + r) * HH + bx + tx] = f2bf(v);
  }
  __syncthreads();
  for (int r = 0; r < 32; r += 8)
    W2Tb[(bx + ty + r) * HH + by + tx] = f2bf(tile[tx][ty + r]);
}

// ---------------------------------------------------------------------------
// K1: per-sample layer 1 (K=48, VALU fp32) + potential
//   outputs: T1b[b][j] bf16, D1[b][j] fp32, POT[b]
// ---------------------------------------------------------------------------
__global__ __launch_bounds__(256) void k_l1pot(
    const float* __restrict__ X, const float* __restrict__ ATOM,
    const float* __restrict__ Z, const float* __restrict__ W1,
    const float* __restrict__ B1,
    ushort* __restrict__ T1b, float* __restrict__ D1,
    float* __restrict__ POT) {
  const int b = blockIdx.x, tid = threadIdx.x;
  __shared__ float xs[DD];
  __shared__ float red[256];

  if (tid < DD) xs[tid] = X[b * DD + tid];
  __syncthreads();

  // ---- layer 1: a1 = x@W1 + b1 ; two j per thread
  {
    const int j0 = tid * 2;
    float acc0 = B1[j0], acc1 = B1[j0 + 1];
#pragma unroll 8
    for (int i = 0; i < DD; ++i) {
      float xv = xs[i];
      float2 w = *reinterpret_cast<const float2*>(&W1[i * HH + j0]);
      acc0 = fmaf(xv, w.x, acc0);
      acc1 = fmaf(xv, w.y, acc1);
    }
    float t0 = tanhf(acc0), t1v = tanhf(acc1);
    unsigned int pk = ((unsigned int)f2bf(t1v) << 16) | f2bf(t0);
    *reinterpret_cast<unsigned int*>(&T1b[b * HH + j0]) = pk;
    *reinterpret_cast<float2*>(&D1[b * HH + j0]) =
        make_float2(1.f - t0 * t0, 1.f - t1v * t1v);
  }

  // ---- potential (deterministic tree reduction)
  {
    float p = 0.f;
    for (int pr = tid; pr < NE * (NE - 1) / 2; pr += 256) {
      int i = 0, rem = pr;
      while (rem >= NE - 1 - i) { rem -= NE - 1 - i; ++i; }
      int j = i + 1 + rem;
      float dx = xs[i * 3 + 0] - xs[j * 3 + 0];
      float dy = xs[i * 3 + 1] - xs[j * 3 + 1];
      float dz = xs[i * 3 + 2] - xs[j * 3 + 2];
      float r = fmaxf(sqrtf(dx * dx + dy * dy + dz * dz), 1e-10f);
      p += 1.f / r;
    }
    for (int idx = tid; idx < NE * NA; idx += 256) {
      int e = idx / NA, a = idx % NA;
      float dx = xs[e * 3 + 0] - ATOM[a * 3 + 0];
      float dy = xs[e * 3 + 1] - ATOM[a * 3 + 1];
      float dz = xs[e * 3 + 2] - ATOM[a * 3 + 2];
      float r = fmaxf(sqrtf(dx * dx + dy * dy + dz * dz), 1e-10f);
      p -= Z[a] / r;
    }
    if (tid == 0) {
      for (int a = 0; a < NA; ++a)
        for (int a2 = a + 1; a2 < NA; ++a2) {
          float dx = ATOM[a * 3 + 0] - ATOM[a2 * 3 + 0];
          float dy = ATOM[a * 3 + 1] - ATOM[a2 * 3 + 1];
          float dz = ATOM[a * 3 + 2] - ATOM[a2 * 3 + 2];
          float r = sqrtf(dx * dx + dy * dy + dz * dz);
          if (r > 1e-10f) p += Z[a] * Z[a2] / r;
        }
    }
    red[tid] = p;
    __syncthreads();
    for (int s = 128; s > 0; s >>= 1) {
      if (tid < s) red[tid] += red[tid + s];
      __syncthreads();
    }
    if (tid == 0) POT[b] = fminf(fmaxf(red[0], -1000.f), 1000.f);
  }
}

// ---------------------------------------------------------------------------
// K2a: A2 = T1b @ W2  (B = W2Tb, [col=k][j]); epilogue: t2/d2 activations
//   C2[b][k] = -2*t2*d2*w3[k] (fp32), Vb[b][k] = bf16(w3[k]*d2)
// ---------------------------------------------------------------------------
__global__ __launch_bounds__(256) void k_gemm_act(
    const ushort* __restrict__ Ab, const ushort* __restrict__ Bb,
    const float* __restrict__ B2, const float* __restrict__ w3,
    float* __restrict__ C2, ushort* __restrict__ Vb) {
  const int cb = blockIdx.x;        // 0..3
  const int rb = blockIdx.y;        // 0..7
  const int row0 = rb * GBM;
  const int col0 = cb * GBN;
  const int t = threadIdx.x;

  __shared__ ushort As[GBM * GBK];
  __shared__ ushort Bs[GBN * GBK];

  const int sr = t >> 1;
  const int skh = (t & 1) * 32;
  const ushort* __restrict__ ap = &Ab[(row0 + sr) * HH];
  const ushort* __restrict__ bp = &Bb[(col0 + sr) * HH];

  const int wave = t >> 6, lane = t & 63;
  const int wm = wave >> 1, wn = wave & 1;
  const int lr = lane & 15, lg = lane >> 4;

  f32x4 acc[4][4];
#pragma unroll
  for (int m = 0; m < 4; ++m)
#pragma unroll
    for (int n = 0; n < 4; ++n) acc[m][n] = (f32x4)0.f;

  for (int kt = 0; kt < HH; kt += GBK) {
#pragma unroll
    for (int q = 0; q < 4; ++q) {
      const int k = kt + skh + q * 8;
      *reinterpret_cast<u16x8*>(&As[swz(sr, (skh >> 3) + q)]) =
          *reinterpret_cast<const u16x8*>(&ap[k]);
      *reinterpret_cast<u16x8*>(&Bs[swz(sr, (skh >> 3) + q)]) =
          *reinterpret_cast<const u16x8*>(&bp[k]);
    }
    __syncthreads();
#pragma unroll
    for (int k0 = 0; k0 < GBK; k0 += 32) {
      const int ck = (k0 >> 3) + lg;
      bf16x8 af[4], bfr[4];
#pragma unroll
      for (int m = 0; m < 4; ++m)
        af[m] = *reinterpret_cast<const bf16x8*>(&As[swz(wm * 64 + m * 16 + lr, ck)]);
#pragma unroll
      for (int n = 0; n < 4; ++n)
        bfr[n] = *reinterpret_cast<const bf16x8*>(&Bs[swz(wn * 64 + n * 16 + lr, ck)]);
#pragma unroll
      for (int m = 0; m < 4; ++m)
#pragma unroll
        for (int n = 0; n < 4; ++n)
          acc[m][n] = __builtin_amdgcn_mfma_f32_16x16x32_bf16(af[m], bfr[n],
                                                              acc[m][n], 0, 0, 0);
    }
    __syncthreads();
  }

#pragma unroll
  for (int m = 0; m < 4; ++m)
#pragma unroll
    for (int e = 0; e < 4; ++e) {
      const int row = row0 + wm * 64 + m * 16 + lg * 4 + e;
#pragma unroll
      for (int n = 0; n < 4; ++n) {
        const int col = col0 + wn * 64 + n * 16 + lr;
        float a2 = acc[m][n][e] + B2[col];
        float t2 = tanhf(a2);
        float d2 = 1.f - t2 * t2;
        float w3v = w3[col];
        C2[row * HH + col] = -2.f * t2 * d2 * w3v;
        Vb[row * HH + col] = f2bf(w3v * d2);
      }
    }
}

// ---------------------------------------------------------------------------
// K2b: U = Vb @ W2^T  (B = W2b, [col=j][k]); epilogue:
//   S1[b][j] = d1*u (fp32), C1[b][j] = -2*t1*d1*u (fp32)
// ---------------------------------------------------------------------------
__global__ __launch_bounds__(256) void k_gemm_u(
    const ushort* __restrict__ Ab, const ushort* __restrict__ Bb,
    const float* __restrict__ D1, const ushort* __restrict__ T1b,
    float* __restrict__ S1, float* __restrict__ C1) {
  const int cb = blockIdx.x;
  const int rb = blockIdx.y;
  const int row0 = rb * GBM;
  const int col0 = cb * GBN;
  const int t = threadIdx.x;

  __shared__ ushort As[GBM * GBK];
  __shared__ ushort Bs[GBN * GBK];

  const int sr = t >> 1;
  const int skh = (t & 1) * 32;
  const ushort* __restrict__ ap = &Ab[(row0 + sr) * HH];
  const ushort* __restrict__ bp = &Bb[(col0 + sr) * HH];

  const int wave = t >> 6, lane = t & 63;
  const int wm = wave >> 1, wn = wave & 1;
  const int lr = lane & 15, lg = lane >> 4;

  f32x4 acc[4][4];
#pragma unroll
  for (int m = 0; m < 4; ++m)
#pragma unroll
    for (int n = 0; n < 4; ++n) acc[m][n] = (f32x4)0.f;

  for (int kt = 0; kt < HH; kt += GBK) {
#pragma unroll
    for (int q = 0; q < 4; ++q) {
      const int k = kt + skh + q * 8;
      *reinterpret_cast<u16x8*>(&As[swz(sr, (skh >> 3) + q)]) =
          *reinterpret_cast<const u16x8*>(&ap[k]);
      *reinterpret_cast<u16x8*>(&Bs[swz(sr, (skh >> 3) + q)]) =
          *reinterpret_cast<const u16x8*>(&bp[k]);
    }
    __syncthreads();
#pragma unroll
    for (int k0 = 0; k0 < GBK; k0 += 32) {
      const int ck = (k0 >> 3) + lg;
      bf16x8 af[4], bfr[4];
#pragma unroll
      for (int m = 0; m < 4; ++m)
        af[m] = *reinterpret_cast<const bf16x8*>(&As[swz(wm * 64 + m * 16 + lr, ck)]);
#pragma unroll
      for (int n = 0; n < 4; ++n)
        bfr[n] = *reinterpret_cast<const bf16x8*>(&Bs[swz(wn * 64 + n * 16 + lr, ck)]);
#pragma unroll
      for (int m = 0; m < 4; ++m)
#pragma unroll
        for (int n = 0; n < 4; ++n)
          acc[m][n] = __builtin_amdgcn_mfma_f32_16x16x32_bf16(af[m], bfr[n],
                                                              acc[m][n], 0, 0, 0);
    }
    __syncthreads();
  }

#pragma unroll
  for (int m = 0; m < 4; ++m)
#pragma unroll
    for (int e = 0; e < 4; ++e) {
      const int row = row0 + wm * 64 + m * 16 + lg * 4 + e;
#pragma unroll
      for (int n = 0; n < 4; ++n) {
        const int col = col0 + wn * 64 + n * 16 + lr;
        float u = acc[m][n][e];
        float d1 = D1[row * HH + col];
        float t1 = bf2f(T1b[row * HH + col]);
        S1[row * HH + col] = d1 * u;
        C1[row * HH + col] = -2.f * t1 * d1 * u;
      }
    }
}

// ---------------------------------------------------------------------------
// K3 (MFMA): Mbig[49152,512] = Abig @ W2, Abig[b*48+i][j] = W1[i,j]*D1[b,j]
//   fused epilogue HD2P[cb][row] = sum_{k in col-block} C2[b,k]*m^2.
// ---------------------------------------------------------------------------
__global__ __launch_bounds__(256) void k_mgemm_mfma(
    const float* __restrict__ W1, const ushort* __restrict__ W2Tb,
    const float* __restrict__ D1, const float* __restrict__ C2,
    float* __restrict__ HD2P) {
  const int cb = blockIdx.x;        // 0..3
  const int rb = blockIdx.y;        // 0..383
  const int row0 = rb * GBM;
  const int col0 = cb * GBN;
  const int t = threadIdx.x;

  __shared__ ushort As[GBM * GBK];
  __shared__ ushort Bs[GBN * GBK];

  const int sr = t >> 1;
  const int skh = (t & 1) * 32;
  const int grow = row0 + sr;
  const int bsmp = grow / DD;
  const int rw = grow - bsmp * DD;
  const float* __restrict__ w1p = &W1[rw * HH];
  const float* __restrict__ d1p = &D1[bsmp * HH];
  const ushort* __restrict__ bp = &W2Tb[(col0 + sr) * HH];

  const int wave = t >> 6, lane = t & 63;
  const int wm = wave >> 1, wn = wave & 1;
  const int lr = lane & 15, lg = lane >> 4;

  f32x4 acc[4][4];
#pragma unroll
  for (int m = 0; m < 4; ++m)
#pragma unroll
    for (int n = 0; n < 4; ++n) acc[m][n] = (f32x4)0.f;

  for (int kt = 0; kt < HH; kt += GBK) {
#pragma unroll
    for (int q = 0; q < 4; ++q) {
      const int k = kt + skh + q * 8;
      float4 wa = *reinterpret_cast<const float4*>(&w1p[k]);
      float4 wb = *reinterpret_cast<const float4*>(&w1p[k + 4]);
      float4 da = *reinterpret_cast<const float4*>(&d1p[k]);
      float4 db = *reinterpret_cast<const float4*>(&d1p[k + 4]);
      u16x8 pk;
      pk[0] = f2bf(wa.x * da.x); pk[1] = f2bf(wa.y * da.y);
      pk[2] = f2bf(wa.z * da.z); pk[3] = f2bf(wa.w * da.w);
      pk[4] = f2bf(wb.x * db.x); pk[5] = f2bf(wb.y * db.y);
      pk[6] = f2bf(wb.z * db.z); pk[7] = f2bf(wb.w * db.w);
      *reinterpret_cast<u16x8*>(&As[swz(sr, (skh >> 3) + q)]) = pk;
      *reinterpret_cast<u16x8*>(&Bs[swz(sr, (skh >> 3) + q)]) =
          *reinterpret_cast<const u16x8*>(&bp[k]);
    }
    __syncthreads();
#pragma unroll
    for (int k0 = 0; k0 < GBK; k0 += 32) {
      const int ck = (k0 >> 3) + lg;
      bf16x8 af[4], bfr[4];
#pragma unroll
      for (int m = 0; m < 4; ++m)
        af[m] = *reinterpret_cast<const bf16x8*>(&As[swz(wm * 64 + m * 16 + lr, ck)]);
#pragma unroll
      for (int n = 0; n < 4; ++n)
        bfr[n] = *reinterpret_cast<const bf16x8*>(&Bs[swz(wn * 64 + n * 16 + lr, ck)]);
#pragma unroll
      for (int m = 0; m < 4; ++m)
#pragma unroll
        for (int n = 0; n < 4; ++n)
          acc[m][n] = __builtin_amdgcn_mfma_f32_16x16x32_bf16(af[m], bfr[n],
                                                              acc[m][n], 0, 0, 0);
    }
    __syncthreads();
  }

#pragma unroll
  for (int m = 0; m < 4; ++m) {
#pragma unroll
    for (int e = 0; e < 4; ++e) {
      const int row_g = row0 + wm * 64 + m * 16 + lg * 4 + e;
      const int bs2 = row_g / DD;
      const float* __restrict__ c2p = &C2[bs2 * HH + col0 + wn * 64 + lr];
      float s = 0.f;
#pragma unroll
      for (int n = 0; n < 4; ++n) {
        float mv = acc[m][n][e];
        s = fmaf(c2p[n * 16] * mv, mv, s);
      }
      s += __shfl_xor(s, 1);
      s += __shfl_xor(s, 2);
      s += __shfl_xor(s, 4);
      s += __shfl_xor(s, 8);
      if (lr == 0) HD2P[cb * ROWS + row_g] = s;
    }
  }
}

// ---------------------------------------------------------------------------
// K4: per-sample grad/hdiag reduce + finalize
//   g_i = sum_j W1[i,j] S1[b,j]; hd1_i = sum_j W1[i,j]^2 C1[b,j]
//   out[b] = clip(-0.5*(lap+gsq), +-100) + POT[b]
// ---------------------------------------------------------------------------
__global__ __launch_bounds__(256) void k_grad_fin(
    const float* __restrict__ W1, const float* __restrict__ S1,
    const float* __restrict__ C1, const float* __restrict__ HD2P,
    const float* __restrict__ POT, float* __restrict__ OUT) {
  const int b = blockIdx.x, tid = threadIdx.x;
  __shared__ float gtmp[DD], htmp[DD];
  const int wid = tid >> 6, lane = tid & 63;

  for (int i = wid; i < DD; i += 4) {
    float gp = 0.f, hp = 0.f;
    for (int j = lane; j < HH; j += 64) {
      float w = W1[i * HH + j];
      gp = fmaf(w, S1[b * HH + j], gp);
      hp = fmaf(w * w, C1[b * HH + j], hp);
    }
#pragma unroll
    for (int off = 32; off > 0; off >>= 1) {
      gp += __shfl_down(gp, off);
      hp += __shfl_down(hp, off);
    }
    if (lane == 0) { gtmp[i] = gp; htmp[i] = hp; }
  }
  __syncthreads();

  if (tid < 64) {
    float gv = 0.f, hv = 0.f;
    if (tid < DD) {
      gv = gtmp[tid];
      float h = htmp[tid];
#pragma unroll
      for (int c = 0; c < NCB; ++c) h += HD2P[c * ROWS + b * DD + tid];
      if (h >= -1e30f && h <= 1e30f) h = fminf(fmaxf(h, -50.f), 50.f);
      else h = 0.f;
      hv = h;
    }
    float sq = gv * gv;
#pragma unroll
    for (int off = 32; off > 0; off >>= 1) {
      sq += __shfl_down(sq, off);
      hv += __shfl_down(hv, off);
    }
    if (tid == 0) {
      float kin = fminf(fmaxf(-0.5f * (hv + sq), -100.f), 100.f);
      OUT[b] = kin + POT[b];
    }
  }
}

// ---------------------------------------------------------------------------
extern "C" void kernel_launch(void* const* d_in, const int* in_sizes, int n_in,
                              void* d_out, int out_size, void* d_ws, size_t ws_size,
                              hipStream_t stream) {
  const float* X    = (const float*)d_in[0];  // [1024,16,3]
  const float* ATOM = (const float*)d_in[1];  // [4,3]
  const float* Z    = (const float*)d_in[2];  // [4]
  const float* W1   = (const float*)d_in[3];  // [48,512]
  const float* B1   = (const float*)d_in[4];  // [512]
  const float* W2   = (const float*)d_in[5];  // [512,512]
  const float* B2   = (const float*)d_in[6];  // [512]
  const float* w3   = (const float*)d_in[7];  // [512]
  float* out = (float*)d_out;

  float* ws = (float*)d_ws;
  ushort* W2b  = (ushort*)ws;                       // 512*512 bf16 = 131072 fl
  ushort* W2Tb = (ushort*)(ws + 131072);            // 131072 fl
  ushort* T1b  = (ushort*)(ws + 262144);            // 1024*512 bf16 = 262144 fl
  ushort* Vb   = (ushort*)(ws + 524288);            // 262144 fl
  float*  D1   = ws + 786432;                       // 524288
  float*  C2   = D1 + BTOT * HH;                    // 524288
  float*  S1   = C2 + BTOT * HH;                    // 524288
  float*  C1   = S1 + BTOT * HH;                    // 524288
  float*  POT  = C1 + BTOT * HH;                    // 1024
  float*  HD2P = POT + BTOT;                        // 4*49152 (~12.3 MB total)

  k_prep<<<dim3(16, 16), dim3(32, 8), 0, stream>>>(W2, W2b, W2Tb);
  k_l1pot<<<BTOT, 256, 0, stream>>>(X, ATOM, Z, W1, B1, T1b, D1, POT);
  k_gemm_act<<<dim3(NCB, BTOT / GBM), 256, 0, stream>>>(T1b, W2Tb, B2, w3, C2, Vb);
  k_gemm_u<<<dim3(NCB, BTOT / GBM), 256, 0, stream>>>(Vb, W2b, D1, T1b, S1, C1);
  k_mgemm_mfma<<<dim3(NCB, ROWS / GBM), 256, 0, stream>>>(W1, W2Tb, D1, C2, HD2P);
  k_grad_fin<<<BTOT, 256, 0, stream>>>(W1, S1, C1, HD2P, POT, out);
}

// Round 4
// 118.588 us; speedup vs baseline: 4.2149x; 1.4625x over previous
//
#include <hip/hip_runtime.h>
#include <math.h>

// Problem constants (fixed by setup_inputs)
#define BTOT 1024
#define NE   16
#define NA   4
#define DD   48        // NE*3
#define HH   512
#define ROWS (BTOT * DD)   // 49152

// GEMM tile (shared by all MFMA kernels)
#define GBM 128
#define GBN 128
#define GBK 64
#define NCB (HH / GBN)   // 4 column blocks

typedef __attribute__((ext_vector_type(8))) short bf16x8;          // 8 bf16 (4 VGPRs)
typedef __attribute__((ext_vector_type(8))) unsigned short u16x8;
typedef __attribute__((ext_vector_type(4))) float f32x4;

__device__ inline unsigned short f2bf(float f) {
  unsigned int u = __builtin_bit_cast(unsigned int, f);
  u += 0x7fffu + ((u >> 16) & 1u);   // round-to-nearest-even
  return (unsigned short)(u >> 16);
}
__device__ inline float bf2f(unsigned short s) {
  unsigned int u = ((unsigned int)s) << 16;
  return __builtin_bit_cast(float, u);
}

// ushort index of 16B chunk `chunk` of row `row` in a [*][64]-bf16 LDS tile,
// XOR-swizzled so stride-128B column reads spread across 8 bank slots (T2).
__device__ inline int swz(int row, int chunk) {
  return (row << 6) + ((chunk ^ (row & 7)) << 3);
}

// async global->LDS, 16B per lane; LDS dest = wave-uniform base + lane*16
__device__ inline void gload16(const ushort* g, ushort* l) {
  __builtin_amdgcn_global_load_lds(
      (const __attribute__((address_space(1))) unsigned int*)g,
      (__attribute__((address_space(3))) unsigned int*)l, 16, 0, 0);
}

// ---------------------------------------------------------------------------
// Shared MFMA GEMM core: 128x128 tile, BK=64, 4 waves x (64x64).
// Staging via global_load_lds with pre-swizzled global source:
//   LDS linear slot (row, chunk c) must hold global chunk c^(row&7)  (swz
//   involution). Lane l of (wave w, issue q) lands at row=w*32+q*8+(l>>3),
//   c=l&7 -> fetches global chunk (l&7)^(l>>3), constant per lane.
// abase/bbase: operand base + tile_row0*HH (bf16, row-major [row][k], k=HH).
// ---------------------------------------------------------------------------
__device__ inline void gemm_k_loop(const ushort* __restrict__ abase,
                                   const ushort* __restrict__ bbase,
                                   ushort* As, ushort* Bs,
                                   int w, int l, f32x4 acc[4][4]) {
  const int lrow = l >> 3;
  const int cg = (l & 7) ^ lrow;
  const ushort* __restrict__ ap = abase + (w * 32 + lrow) * HH + cg * 8;
  const ushort* __restrict__ bp = bbase + (w * 32 + lrow) * HH + cg * 8;
  const int wm = w >> 1, wn = w & 1;
  const int lr = l & 15, lg = l >> 4;

  for (int kt = 0; kt < HH; kt += GBK) {
#pragma unroll
    for (int q = 0; q < 4; ++q) {
      gload16(ap + kt + q * 8 * HH, As + (w * 4 + q) * 512);
      gload16(bp + kt + q * 8 * HH, Bs + (w * 4 + q) * 512);
    }
    __syncthreads();   // compiler drains vmcnt(0) before s_barrier
#pragma unroll
    for (int k0 = 0; k0 < GBK; k0 += 32) {
      const int ck = (k0 >> 3) + lg;
      bf16x8 af[4], bfr[4];
#pragma unroll
      for (int m = 0; m < 4; ++m)
        af[m] = *reinterpret_cast<const bf16x8*>(&As[swz(wm * 64 + m * 16 + lr, ck)]);
#pragma unroll
      for (int n = 0; n < 4; ++n)
        bfr[n] = *reinterpret_cast<const bf16x8*>(&Bs[swz(wn * 64 + n * 16 + lr, ck)]);
#pragma unroll
      for (int m = 0; m < 4; ++m)
#pragma unroll
        for (int n = 0; n < 4; ++n)
          acc[m][n] = __builtin_amdgcn_mfma_f32_16x16x32_bf16(af[m], bfr[n],
                                                              acc[m][n], 0, 0, 0);
    }
    __syncthreads();
  }
}

// ---------------------------------------------------------------------------
// K0: W2 -> W2b (bf16 row-major) and W2Tb (bf16 transpose)
// ---------------------------------------------------------------------------
__global__ __launch_bounds__(256) void k_prep(const float* __restrict__ W2,
                                              ushort* __restrict__ W2b,
                                              ushort* __restrict__ W2Tb) {
  __shared__ float tile[32][33];
  int bx = blockIdx.x * 32, by = blockIdx.y * 32;
  int tx = threadIdx.x, ty = threadIdx.y;  // (32, 8)
  for (int r = 0; r < 32; r += 8) {
    float v = W2[(by + ty + r) * HH + bx + tx];
    tile[ty + r][tx] = v;
    W2b[(by + ty + r) * HH + bx + tx] = f2bf(v);
  }
  __syncthreads();
  for (int r = 0; r < 32; r += 8)
    W2Tb[(bx + ty + r) * HH + by + tx] = f2bf(tile[tx][ty + r]);
}

// ---------------------------------------------------------------------------
// K1: per-sample layer 1 (K=48, VALU fp32) + Ab panel build + potential
//   outputs: T1b[b][j] bf16, D1[b][j] fp32, Ab[b*48+i][k] bf16, POT[b]
// ---------------------------------------------------------------------------
__global__ __launch_bounds__(256) void k_l1pot(
    const float* __restrict__ X, const float* __restrict__ ATOM,
    const float* __restrict__ Z, const float* __restrict__ W1,
    const float* __restrict__ B1,
    ushort* __restrict__ T1b, float* __restrict__ D1,
    ushort* __restrict__ Ab, float* __restrict__ POT) {
  const int b = blockIdx.x, tid = threadIdx.x;
  __shared__ float xs[DD];
  __shared__ float d1s[HH];
  __shared__ float red[256];

  if (tid < DD) xs[tid] = X[b * DD + tid];
  __syncthreads();

  // ---- layer 1: a1 = x@W1 + b1 ; two j per thread
  {
    const int j0 = tid * 2;
    float acc0 = B1[j0], acc1 = B1[j0 + 1];
#pragma unroll 8
    for (int i = 0; i < DD; ++i) {
      float xv = xs[i];
      float2 w = *reinterpret_cast<const float2*>(&W1[i * HH + j0]);
      acc0 = fmaf(xv, w.x, acc0);
      acc1 = fmaf(xv, w.y, acc1);
    }
    float t0 = tanhf(acc0), t1v = tanhf(acc1);
    unsigned int pk = ((unsigned int)f2bf(t1v) << 16) | f2bf(t0);
    *reinterpret_cast<unsigned int*>(&T1b[b * HH + j0]) = pk;
    float dd0 = 1.f - t0 * t0, dd1 = 1.f - t1v * t1v;
    d1s[j0] = dd0; d1s[j0 + 1] = dd1;
    *reinterpret_cast<float2*>(&D1[b * HH + j0]) = make_float2(dd0, dd1);
  }
  __syncthreads();

  // ---- Ab panel: Ab[b*48+i][k] = bf16(W1[i,k]*d1[k]); thread covers k=2*tid
  {
    const int k0 = tid * 2;
    const float dd0 = d1s[k0], dd1 = d1s[k0 + 1];
#pragma unroll 4
    for (int i = 0; i < DD; ++i) {
      float2 w = *reinterpret_cast<const float2*>(&W1[i * HH + k0]);
      unsigned int pk =
          ((unsigned int)f2bf(w.y * dd1) << 16) | f2bf(w.x * dd0);
      *reinterpret_cast<unsigned int*>(&Ab[(b * DD + i) * HH + k0]) = pk;
    }
  }

  // ---- potential (deterministic tree reduction)
  {
    float p = 0.f;
    for (int pr = tid; pr < NE * (NE - 1) / 2; pr += 256) {
      int i = 0, rem = pr;
      while (rem >= NE - 1 - i) { rem -= NE - 1 - i; ++i; }
      int j = i + 1 + rem;
      float dx = xs[i * 3 + 0] - xs[j * 3 + 0];
      float dy = xs[i * 3 + 1] - xs[j * 3 + 1];
      float dz = xs[i * 3 + 2] - xs[j * 3 + 2];
      float r = fmaxf(sqrtf(dx * dx + dy * dy + dz * dz), 1e-10f);
      p += 1.f / r;
    }
    for (int idx = tid; idx < NE * NA; idx += 256) {
      int e = idx / NA, a = idx % NA;
      float dx = xs[e * 3 + 0] - ATOM[a * 3 + 0];
      float dy = xs[e * 3 + 1] - ATOM[a * 3 + 1];
      float dz = xs[e * 3 + 2] - ATOM[a * 3 + 2];
      float r = fmaxf(sqrtf(dx * dx + dy * dy + dz * dz), 1e-10f);
      p -= Z[a] / r;
    }
    if (tid == 0) {
      for (int a = 0; a < NA; ++a)
        for (int a2 = a + 1; a2 < NA; ++a2) {
          float dx = ATOM[a * 3 + 0] - ATOM[a2 * 3 + 0];
          float dy = ATOM[a * 3 + 1] - ATOM[a2 * 3 + 1];
          float dz = ATOM[a * 3 + 2] - ATOM[a2 * 3 + 2];
          float r = sqrtf(dx * dx + dy * dy + dz * dz);
          if (r > 1e-10f) p += Z[a] * Z[a2] / r;
        }
    }
    red[tid] = p;
    __syncthreads();
    for (int s = 128; s > 0; s >>= 1) {
      if (tid < s) red[tid] += red[tid + s];
      __syncthreads();
    }
    if (tid == 0) POT[b] = fminf(fmaxf(red[0], -1000.f), 1000.f);
  }
}

// ---------------------------------------------------------------------------
// K2a: A2 = T1b @ W2  (B = W2Tb); epilogue: t2/d2 activations
//   C2[b][k] = -2*t2*d2*w3[k] (fp32), Vb[b][k] = bf16(w3[k]*d2)
// ---------------------------------------------------------------------------
__global__ __launch_bounds__(256) void k_gemm_act(
    const ushort* __restrict__ Ab, const ushort* __restrict__ Bb,
    const float* __restrict__ B2, const float* __restrict__ w3,
    float* __restrict__ C2, ushort* __restrict__ Vb) {
  const int cb = blockIdx.x & 3;
  const int rb = blockIdx.x >> 2;
  const int row0 = rb * GBM, col0 = cb * GBN;
  const int t = threadIdx.x, w = t >> 6, l = t & 63;

  __shared__ ushort As[GBM * GBK];
  __shared__ ushort Bs[GBN * GBK];

  f32x4 acc[4][4];
#pragma unroll
  for (int m = 0; m < 4; ++m)
#pragma unroll
    for (int n = 0; n < 4; ++n) acc[m][n] = (f32x4)0.f;

  gemm_k_loop(Ab + row0 * HH, Bb + col0 * HH, As, Bs, w, l, acc);

  const int wm = w >> 1, wn = w & 1, lr = l & 15, lg = l >> 4;
#pragma unroll
  for (int m = 0; m < 4; ++m)
#pragma unroll
    for (int e = 0; e < 4; ++e) {
      const int row = row0 + wm * 64 + m * 16 + lg * 4 + e;
#pragma unroll
      for (int n = 0; n < 4; ++n) {
        const int col = col0 + wn * 64 + n * 16 + lr;
        float a2 = acc[m][n][e] + B2[col];
        float t2 = tanhf(a2);
        float d2 = 1.f - t2 * t2;
        float w3v = w3[col];
        C2[row * HH + col] = -2.f * t2 * d2 * w3v;
        Vb[row * HH + col] = f2bf(w3v * d2);
      }
    }
}

// ---------------------------------------------------------------------------
// K2b: U = Vb @ W2^T  (B = W2b); epilogue:
//   S1[b][j] = d1*u (fp32), C1[b][j] = -2*t1*d1*u (fp32)
// ---------------------------------------------------------------------------
__global__ __launch_bounds__(256) void k_gemm_u(
    const ushort* __restrict__ Ab, const ushort* __restrict__ Bb,
    const float* __restrict__ D1, const ushort* __restrict__ T1b,
    float* __restrict__ S1, float* __restrict__ C1) {
  const int cb = blockIdx.x & 3;
  const int rb = blockIdx.x >> 2;
  const int row0 = rb * GBM, col0 = cb * GBN;
  const int t = threadIdx.x, w = t >> 6, l = t & 63;

  __shared__ ushort As[GBM * GBK];
  __shared__ ushort Bs[GBN * GBK];

  f32x4 acc[4][4];
#pragma unroll
  for (int m = 0; m < 4; ++m)
#pragma unroll
    for (int n = 0; n < 4; ++n) acc[m][n] = (f32x4)0.f;

  gemm_k_loop(Ab + row0 * HH, Bb + col0 * HH, As, Bs, w, l, acc);

  const int wm = w >> 1, wn = w & 1, lr = l & 15, lg = l >> 4;
#pragma unroll
  for (int m = 0; m < 4; ++m)
#pragma unroll
    for (int e = 0; e < 4; ++e) {
      const int row = row0 + wm * 64 + m * 16 + lg * 4 + e;
#pragma unroll
      for (int n = 0; n < 4; ++n) {
        const int col = col0 + wn * 64 + n * 16 + lr;
        float u = acc[m][n][e];
        float d1 = D1[row * HH + col];
        float t1 = bf2f(T1b[row * HH + col]);
        S1[row * HH + col] = d1 * u;
        C1[row * HH + col] = -2.f * t1 * d1 * u;
      }
    }
}

// ---------------------------------------------------------------------------
// K3: M = Ab(49152x512) @ W2 (B = W2Tb); fused epilogue
//   HD2P[cb][row] = sum_{k in col-block} C2[b,k]*m^2
//   Grid 1536 1D, bijective XCD swizzle, cb fastest within an XCD chunk so
//   the 4 col-blocks of one A-panel share L2.
// ---------------------------------------------------------------------------
__global__ __launch_bounds__(256) void k_mgemm_mfma(
    const ushort* __restrict__ Ab, const ushort* __restrict__ W2Tb,
    const float* __restrict__ C2, float* __restrict__ HD2P) {
  const int bid = blockIdx.x;
  const int wgid = (bid & 7) * (ROWS / GBM * NCB / 8) + (bid >> 3);  // 1536%8==0
  const int cb = wgid & 3;
  const int rb = wgid >> 2;
  const int row0 = rb * GBM, col0 = cb * GBN;
  const int t = threadIdx.x, w = t >> 6, l = t & 63;

  __shared__ ushort As[GBM * GBK];
  __shared__ ushort Bs[GBN * GBK];

  f32x4 acc[4][4];
#pragma unroll
  for (int m = 0; m < 4; ++m)
#pragma unroll
    for (int n = 0; n < 4; ++n) acc[m][n] = (f32x4)0.f;

  gemm_k_loop(Ab + row0 * HH, W2Tb + col0 * HH, As, Bs, w, l, acc);

  const int wm = w >> 1, wn = w & 1, lr = l & 15, lg = l >> 4;
#pragma unroll
  for (int m = 0; m < 4; ++m) {
#pragma unroll
    for (int e = 0; e < 4; ++e) {
      const int row_g = row0 + wm * 64 + m * 16 + lg * 4 + e;
      const int bs2 = row_g / DD;
      const float* __restrict__ c2p = &C2[bs2 * HH + col0 + wn * 64 + lr];
      float s = 0.f;
#pragma unroll
      for (int n = 0; n < 4; ++n) {
        float mv = acc[m][n][e];
        s = fmaf(c2p[n * 16] * mv, mv, s);
      }
      s += __shfl_xor(s, 1);
      s += __shfl_xor(s, 2);
      s += __shfl_xor(s, 4);
      s += __shfl_xor(s, 8);
      if (lr == 0) HD2P[cb * ROWS + row_g] = s;
    }
  }
}

// ---------------------------------------------------------------------------
// K4: per-sample grad/hdiag reduce + finalize
// ---------------------------------------------------------------------------
__global__ __launch_bounds__(256) void k_grad_fin(
    const float* __restrict__ W1, const float* __restrict__ S1,
    const float* __restrict__ C1, const float* __restrict__ HD2P,
    const float* __restrict__ POT, float* __restrict__ OUT) {
  const int b = blockIdx.x, tid = threadIdx.x;
  __shared__ float gtmp[DD], htmp[DD];
  const int wid = tid >> 6, lane = tid & 63;

  for (int i = wid; i < DD; i += 4) {
    float gp = 0.f, hp = 0.f;
#pragma unroll
    for (int it = 0; it < 4; ++it) {
      const int j = it * 128 + lane * 2;
      float2 wv = *reinterpret_cast<const float2*>(&W1[i * HH + j]);
      float2 sv = *reinterpret_cast<const float2*>(&S1[b * HH + j]);
      float2 cv = *reinterpret_cast<const float2*>(&C1[b * HH + j]);
      gp = fmaf(wv.x, sv.x, gp); gp = fmaf(wv.y, sv.y, gp);
      hp = fmaf(wv.x * wv.x, cv.x, hp); hp = fmaf(wv.y * wv.y, cv.y, hp);
    }
#pragma unroll
    for (int off = 32; off > 0; off >>= 1) {
      gp += __shfl_down(gp, off);
      hp += __shfl_down(hp, off);
    }
    if (lane == 0) { gtmp[i] = gp; htmp[i] = hp; }
  }
  __syncthreads();

  if (tid < 64) {
    float gv = 0.f, hv = 0.f;
    if (tid < DD) {
      gv = gtmp[tid];
      float h = htmp[tid];
#pragma unroll
      for (int c = 0; c < NCB; ++c) h += HD2P[c * ROWS + b * DD + tid];
      if (h >= -1e30f && h <= 1e30f) h = fminf(fmaxf(h, -50.f), 50.f);
      else h = 0.f;
      hv = h;
    }
    float sq = gv * gv;
#pragma unroll
    for (int off = 32; off > 0; off >>= 1) {
      sq += __shfl_down(sq, off);
      hv += __shfl_down(hv, off);
    }
    if (tid == 0) {
      float kin = fminf(fmaxf(-0.5f * (hv + sq), -100.f), 100.f);
      OUT[b] = kin + POT[b];
    }
  }
}

// ---------------------------------------------------------------------------
extern "C" void kernel_launch(void* const* d_in, const int* in_sizes, int n_in,
                              void* d_out, int out_size, void* d_ws, size_t ws_size,
                              hipStream_t stream) {
  const float* X    = (const float*)d_in[0];  // [1024,16,3]
  const float* ATOM = (const float*)d_in[1];  // [4,3]
  const float* Z    = (const float*)d_in[2];  // [4]
  const float* W1   = (const float*)d_in[3];  // [48,512]
  const float* B1   = (const float*)d_in[4];  // [512]
  const float* W2   = (const float*)d_in[5];  // [512,512]
  const float* B2   = (const float*)d_in[6];  // [512]
  const float* w3   = (const float*)d_in[7];  // [512]
  float* out = (float*)d_out;

  float* ws = (float*)d_ws;
  ushort* W2b  = (ushort*)ws;                       // 512*512 bf16 = 131072 fl
  ushort* W2Tb = (ushort*)(ws + 131072);            // 131072 fl
  ushort* T1b  = (ushort*)(ws + 262144);            // 262144 fl
  ushort* Vb   = (ushort*)(ws + 524288);            // 262144 fl
  float*  D1   = ws + 786432;                       // 524288
  float*  C2   = D1 + BTOT * HH;                    // 524288
  float*  S1   = C2 + BTOT * HH;                    // 524288
  float*  C1   = S1 + BTOT * HH;                    // 524288
  float*  POT  = C1 + BTOT * HH;                    // 1024
  float*  HD2P = POT + BTOT;                        // 4*49152
  ushort* Abig = (ushort*)(HD2P + NCB * ROWS);      // 49152*512 bf16 (~50 MB; ~63 MB total)

  k_prep<<<dim3(16, 16), dim3(32, 8), 0, stream>>>(W2, W2b, W2Tb);
  k_l1pot<<<BTOT, 256, 0, stream>>>(X, ATOM, Z, W1, B1, T1b, D1, Abig, POT);
  k_gemm_act<<<NCB * (BTOT / GBM), 256, 0, stream>>>(T1b, W2Tb, B2, w3, C2, Vb);
  k_gemm_u<<<NCB * (BTOT / GBM), 256, 0, stream>>>(Vb, W2b, D1, T1b, S1, C1);
  k_mgemm_mfma<<<NCB * (ROWS / GBM), 256, 0, stream>>>(Abig, W2Tb, C2, HD2P);
  k_grad_fin<<<BTOT, 256, 0, stream>>>(W1, S1, C1, HD2P, POT, out);
}

// Round 5
// 88.041 us; speedup vs baseline: 5.6774x; 1.3470x over previous
//
#include <hip/hip_runtime.h>
#include <math.h>

// Problem constants (fixed by setup_inputs)
#define BTOT 1024
#define NE   16
#define NA   4
#define DD   48        // NE*3
#define HH   512
#define ROWS (BTOT * DD)   // 49152

// Large GEMM tile (mgemm)
#define GBM 128
#define GBN 128
#define GBK 64
#define NCB (HH / GBN)            // 4 column blocks
#define MG  (NCB * (ROWS / GBM))  // 1536 mgemm blocks

typedef __attribute__((ext_vector_type(8))) short bf16x8;          // 8 bf16 (4 VGPRs)
typedef __attribute__((ext_vector_type(8))) unsigned short u16x8;
typedef __attribute__((ext_vector_type(4))) float f32x4;

__device__ inline unsigned short f2bf(float f) {
  unsigned int u = __builtin_bit_cast(unsigned int, f);
  u += 0x7fffu + ((u >> 16) & 1u);   // round-to-nearest-even
  return (unsigned short)(u >> 16);
}
__device__ inline float bf2f(unsigned short s) {
  unsigned int u = ((unsigned int)s) << 16;
  return __builtin_bit_cast(float, u);
}

// ushort index of 16B chunk `chunk` of row `row` in a [*][64]-bf16 LDS tile,
// XOR-swizzled so stride-128B column reads spread across 8 bank slots (T2).
// Verified: SQ_LDS_BANK_CONFLICT == 0 in R3/R4.
__device__ inline int swz(int row, int chunk) {
  return (row << 6) + ((chunk ^ (row & 7)) << 3);
}

// async global->LDS, 16B per lane; LDS dest = wave-uniform base + lane*16
__device__ inline void gload16(const ushort* g, ushort* l) {
  __builtin_amdgcn_global_load_lds(
      (const __attribute__((address_space(1))) unsigned int*)g,
      (__attribute__((address_space(3))) unsigned int*)l, 16, 0, 0);
}

// ---------------------------------------------------------------------------
// 128x128 GEMM K-loop (4 waves x 64x64). Pre-swizzled global source:
//   LDS slot (row, chunk c) holds global chunk c^(row&7); lane l of issue q
//   lands at row = issue*8 + (l>>3), phys chunk l&7 -> global chunk
//   (l&7)^(l>>3). 16 issues of 1KB per operand per K-tile (4 q x 4 waves).
// ---------------------------------------------------------------------------
__device__ inline void gemm128_k_loop(const ushort* __restrict__ abase,
                                      const ushort* __restrict__ bbase,
                                      ushort* As, ushort* Bs,
                                      int w, int l, f32x4 acc[4][4]) {
  const int lrow = l >> 3;
  const int cg = (l & 7) ^ lrow;
  const ushort* __restrict__ ap = abase + (w * 32 + lrow) * HH + cg * 8;
  const ushort* __restrict__ bp = bbase + (w * 32 + lrow) * HH + cg * 8;
  const int wm = w >> 1, wn = w & 1;
  const int lr = l & 15, lg = l >> 4;

  for (int kt = 0; kt < HH; kt += GBK) {
#pragma unroll
    for (int q = 0; q < 4; ++q) {
      gload16(ap + kt + q * 8 * HH, As + (w * 4 + q) * 512);
      gload16(bp + kt + q * 8 * HH, Bs + (w * 4 + q) * 512);
    }
    __syncthreads();   // drains vmcnt(0) before s_barrier
#pragma unroll
    for (int k0 = 0; k0 < GBK; k0 += 32) {
      const int ck = (k0 >> 3) + lg;
      bf16x8 af[4], bfr[4];
#pragma unroll
      for (int m = 0; m < 4; ++m)
        af[m] = *reinterpret_cast<const bf16x8*>(&As[swz(wm * 64 + m * 16 + lr, ck)]);
#pragma unroll
      for (int n = 0; n < 4; ++n)
        bfr[n] = *reinterpret_cast<const bf16x8*>(&Bs[swz(wn * 64 + n * 16 + lr, ck)]);
#pragma unroll
      for (int m = 0; m < 4; ++m)
#pragma unroll
        for (int n = 0; n < 4; ++n)
          acc[m][n] = __builtin_amdgcn_mfma_f32_16x16x32_bf16(af[m], bfr[n],
                                                              acc[m][n], 0, 0, 0);
    }
    __syncthreads();
  }
}

// ---------------------------------------------------------------------------
// 64x64 GEMM K-loop (4 waves x 32x32) for the small B=1024 GEMMs -> 128-block
// grids (4x the CU coverage of 128x128 at this M).
// ---------------------------------------------------------------------------
__device__ inline void gemm64_k_loop(const ushort* __restrict__ abase,
                                     const ushort* __restrict__ bbase,
                                     ushort* As, ushort* Bs,
                                     int w, int l, f32x4 acc[2][2]) {
  const int lrow = l >> 3;
  const int cg = (l & 7) ^ lrow;
  const ushort* __restrict__ ap = abase + (w * 16 + lrow) * HH + cg * 8;
  const ushort* __restrict__ bp = bbase + (w * 16 + lrow) * HH + cg * 8;
  const int wm = w >> 1, wn = w & 1;
  const int lr = l & 15, lg = l >> 4;

  for (int kt = 0; kt < HH; kt += GBK) {
#pragma unroll
    for (int q = 0; q < 2; ++q) {
      gload16(ap + kt + q * 8 * HH, As + (w * 2 + q) * 512);
      gload16(bp + kt + q * 8 * HH, Bs + (w * 2 + q) * 512);
    }
    __syncthreads();
#pragma unroll
    for (int k0 = 0; k0 < GBK; k0 += 32) {
      const int ck = (k0 >> 3) + lg;
      bf16x8 af[2], bfr[2];
#pragma unroll
      for (int m = 0; m < 2; ++m)
        af[m] = *reinterpret_cast<const bf16x8*>(&As[swz(wm * 32 + m * 16 + lr, ck)]);
#pragma unroll
      for (int n = 0; n < 2; ++n)
        bfr[n] = *reinterpret_cast<const bf16x8*>(&Bs[swz(wn * 32 + n * 16 + lr, ck)]);
#pragma unroll
      for (int m = 0; m < 2; ++m)
#pragma unroll
        for (int n = 0; n < 2; ++n)
          acc[m][n] = __builtin_amdgcn_mfma_f32_16x16x32_bf16(af[m], bfr[n],
                                                              acc[m][n], 0, 0, 0);
    }
    __syncthreads();
  }
}

// ---------------------------------------------------------------------------
// K1: per-sample layer 1 + Ab panel build + potential; blocks < 256 also
//     convert one 32x32 W2 tile -> W2b / W2Tb (fused old k_prep).
// ---------------------------------------------------------------------------
__global__ __launch_bounds__(256) void k_l1pot(
    const float* __restrict__ X, const float* __restrict__ ATOM,
    const float* __restrict__ Z, const float* __restrict__ W1,
    const float* __restrict__ B1, const float* __restrict__ W2,
    ushort* __restrict__ W2b, ushort* __restrict__ W2Tb,
    ushort* __restrict__ T1b, float* __restrict__ D1,
    ushort* __restrict__ Ab, float* __restrict__ POT) {
  const int b = blockIdx.x, tid = threadIdx.x;
  __shared__ float xs[DD];
  __shared__ float d1s[HH];
  __shared__ float red[256];
  __shared__ float tile[32][33];

  // ---- fused W2 conversion (one 32x32 tile per block for b < 256)
  if (b < 256) {
    const int bx = (b & 15) * 32, by = (b >> 4) * 32;
    const int tx = tid & 31, ty = tid >> 5;  // ty 0..7
    for (int r = 0; r < 32; r += 8) {
      float v = W2[(by + ty + r) * HH + bx + tx];
      tile[ty + r][tx] = v;
      W2b[(by + ty + r) * HH + bx + tx] = f2bf(v);
    }
    __syncthreads();
    for (int r = 0; r < 32; r += 8)
      W2Tb[(bx + ty + r) * HH + by + tx] = f2bf(tile[tx][ty + r]);
  }

  if (tid < DD) xs[tid] = X[b * DD + tid];
  __syncthreads();

  // ---- layer 1: a1 = x@W1 + b1 ; two j per thread
  {
    const int j0 = tid * 2;
    float acc0 = B1[j0], acc1 = B1[j0 + 1];
#pragma unroll 8
    for (int i = 0; i < DD; ++i) {
      float xv = xs[i];
      float2 w = *reinterpret_cast<const float2*>(&W1[i * HH + j0]);
      acc0 = fmaf(xv, w.x, acc0);
      acc1 = fmaf(xv, w.y, acc1);
    }
    float t0 = tanhf(acc0), t1v = tanhf(acc1);
    unsigned int pk = ((unsigned int)f2bf(t1v) << 16) | f2bf(t0);
    *reinterpret_cast<unsigned int*>(&T1b[b * HH + j0]) = pk;
    float dd0 = 1.f - t0 * t0, dd1 = 1.f - t1v * t1v;
    d1s[j0] = dd0; d1s[j0 + 1] = dd1;
    *reinterpret_cast<float2*>(&D1[b * HH + j0]) = make_float2(dd0, dd1);
  }
  __syncthreads();

  // ---- Ab panel: Ab[b*48+i][k] = bf16(W1[i,k]*d1[k]); thread covers k=2*tid
  {
    const int k0 = tid * 2;
    const float dd0 = d1s[k0], dd1 = d1s[k0 + 1];
#pragma unroll 4
    for (int i = 0; i < DD; ++i) {
      float2 w = *reinterpret_cast<const float2*>(&W1[i * HH + k0]);
      unsigned int pk =
          ((unsigned int)f2bf(w.y * dd1) << 16) | f2bf(w.x * dd0);
      *reinterpret_cast<unsigned int*>(&Ab[(b * DD + i) * HH + k0]) = pk;
    }
  }

  // ---- potential (deterministic tree reduction)
  {
    float p = 0.f;
    for (int pr = tid; pr < NE * (NE - 1) / 2; pr += 256) {
      int i = 0, rem = pr;
      while (rem >= NE - 1 - i) { rem -= NE - 1 - i; ++i; }
      int j = i + 1 + rem;
      float dx = xs[i * 3 + 0] - xs[j * 3 + 0];
      float dy = xs[i * 3 + 1] - xs[j * 3 + 1];
      float dz = xs[i * 3 + 2] - xs[j * 3 + 2];
      float r = fmaxf(sqrtf(dx * dx + dy * dy + dz * dz), 1e-10f);
      p += 1.f / r;
    }
    for (int idx = tid; idx < NE * NA; idx += 256) {
      int e = idx / NA, a = idx % NA;
      float dx = xs[e * 3 + 0] - ATOM[a * 3 + 0];
      float dy = xs[e * 3 + 1] - ATOM[a * 3 + 1];
      float dz = xs[e * 3 + 2] - ATOM[a * 3 + 2];
      float r = fmaxf(sqrtf(dx * dx + dy * dy + dz * dz), 1e-10f);
      p -= Z[a] / r;
    }
    if (tid == 0) {
      for (int a = 0; a < NA; ++a)
        for (int a2 = a + 1; a2 < NA; ++a2) {
          float dx = ATOM[a * 3 + 0] - ATOM[a2 * 3 + 0];
          float dy = ATOM[a * 3 + 1] - ATOM[a2 * 3 + 1];
          float dz = ATOM[a * 3 + 2] - ATOM[a2 * 3 + 2];
          float r = sqrtf(dx * dx + dy * dy + dz * dz);
          if (r > 1e-10f) p += Z[a] * Z[a2] / r;
        }
    }
    red[tid] = p;
    __syncthreads();
    for (int s = 128; s > 0; s >>= 1) {
      if (tid < s) red[tid] += red[tid + s];
      __syncthreads();
    }
    if (tid == 0) POT[b] = fminf(fmaxf(red[0], -1000.f), 1000.f);
  }
}

// ---------------------------------------------------------------------------
// K2: A2 = T1b @ W2 (B = W2Tb), 64x64 tiles, grid 128; epilogue t2/d2:
//   C2[b][k] = -2*t2*d2*w3[k] (fp32), Vb[b][k] = bf16(w3[k]*d2)
// ---------------------------------------------------------------------------
__global__ __launch_bounds__(256) void k_act64(
    const ushort* __restrict__ Ab, const ushort* __restrict__ Bb,
    const float* __restrict__ B2, const float* __restrict__ w3,
    float* __restrict__ C2, ushort* __restrict__ Vb) {
  const int rb = blockIdx.x >> 3;     // 0..15
  const int cb = blockIdx.x & 7;      // 0..7
  const int row0 = rb * 64, col0 = cb * 64;
  const int t = threadIdx.x, w = t >> 6, l = t & 63;

  __shared__ ushort As[64 * GBK];
  __shared__ ushort Bs[64 * GBK];

  f32x4 acc[2][2];
#pragma unroll
  for (int m = 0; m < 2; ++m)
#pragma unroll
    for (int n = 0; n < 2; ++n) acc[m][n] = (f32x4)0.f;

  gemm64_k_loop(Ab + row0 * HH, Bb + col0 * HH, As, Bs, w, l, acc);

  const int wm = w >> 1, wn = w & 1, lr = l & 15, lg = l >> 4;
#pragma unroll
  for (int m = 0; m < 2; ++m)
#pragma unroll
    for (int e = 0; e < 4; ++e) {
      const int row = row0 + wm * 32 + m * 16 + lg * 4 + e;
#pragma unroll
      for (int n = 0; n < 2; ++n) {
        const int col = col0 + wn * 32 + n * 16 + lr;
        float a2 = acc[m][n][e] + B2[col];
        float t2 = tanhf(a2);
        float d2 = 1.f - t2 * t2;
        float w3v = w3[col];
        C2[row * HH + col] = -2.f * t2 * d2 * w3v;
        Vb[row * HH + col] = f2bf(w3v * d2);
      }
    }
}

// ---------------------------------------------------------------------------
// K3 (merged): blocks < MG run the big m-GEMM (with bijective XCD swizzle,
//   cb fastest so the 4 col-blocks of one A-panel share L2); remaining 128
//   blocks run the U-GEMM (64x64). Outputs disjoint; both only read
//   earlier-launch data -> safe under undefined dispatch order.
// ---------------------------------------------------------------------------
__global__ __launch_bounds__(256) void k_mu(
    const ushort* __restrict__ Abig, const ushort* __restrict__ W2Tb,
    const float* __restrict__ C2, float* __restrict__ HD2P,
    const ushort* __restrict__ Vb, const ushort* __restrict__ W2b,
    const float* __restrict__ D1, const ushort* __restrict__ T1b,
    ushort* __restrict__ S1b, ushort* __restrict__ C1b) {
  const int t = threadIdx.x, w = t >> 6, l = t & 63;
  __shared__ ushort As[GBM * GBK];
  __shared__ ushort Bs[GBN * GBK];

  if (blockIdx.x < MG) {
    // ---- m-GEMM role: M[49152,512] = Abig @ W2, fused c2*m^2 epilogue
    const int bid = blockIdx.x;
    const int wgid = (bid & 7) * (MG / 8) + (bid >> 3);   // 1536 % 8 == 0
    const int cb = wgid & 3;
    const int rb = wgid >> 2;
    const int row0 = rb * GBM, col0 = cb * GBN;

    f32x4 acc[4][4];
#pragma unroll
    for (int m = 0; m < 4; ++m)
#pragma unroll
      for (int n = 0; n < 4; ++n) acc[m][n] = (f32x4)0.f;

    gemm128_k_loop(Abig + row0 * HH, W2Tb + col0 * HH, As, Bs, w, l, acc);

    const int wm = w >> 1, wn = w & 1, lr = l & 15, lg = l >> 4;
#pragma unroll
    for (int m = 0; m < 4; ++m) {
#pragma unroll
      for (int e = 0; e < 4; ++e) {
        const int row_g = row0 + wm * 64 + m * 16 + lg * 4 + e;
        const int bs2 = row_g / DD;
        const float* __restrict__ c2p = &C2[bs2 * HH + col0 + wn * 64 + lr];
        float s = 0.f;
#pragma unroll
        for (int n = 0; n < 4; ++n) {
          float mv = acc[m][n][e];
          s = fmaf(c2p[n * 16] * mv, mv, s);
        }
        s += __shfl_xor(s, 1);
        s += __shfl_xor(s, 2);
        s += __shfl_xor(s, 4);
        s += __shfl_xor(s, 8);
        if (lr == 0) HD2P[cb * ROWS + row_g] = s;
      }
    }
  } else {
    // ---- U-GEMM role: U = Vb @ W2^T (B = W2b), 64x64 tiles
    const int ub = blockIdx.x - MG;     // 0..127
    const int rb = ub >> 3, cb = ub & 7;
    const int row0 = rb * 64, col0 = cb * 64;

    f32x4 acc[2][2];
#pragma unroll
    for (int m = 0; m < 2; ++m)
#pragma unroll
      for (int n = 0; n < 2; ++n) acc[m][n] = (f32x4)0.f;

    gemm64_k_loop(Vb + row0 * HH, W2b + col0 * HH, As, Bs, w, l, acc);

    const int wm = w >> 1, wn = w & 1, lr = l & 15, lg = l >> 4;
#pragma unroll
    for (int m = 0; m < 2; ++m)
#pragma unroll
      for (int e = 0; e < 4; ++e) {
        const int row = row0 + wm * 32 + m * 16 + lg * 4 + e;
#pragma unroll
        for (int n = 0; n < 2; ++n) {
          const int col = col0 + wn * 32 + n * 16 + lr;
          float u = acc[m][n][e];
          float d1 = D1[row * HH + col];
          float t1 = bf2f(T1b[row * HH + col]);
          S1b[row * HH + col] = f2bf(d1 * u);
          C1b[row * HH + col] = f2bf(-2.f * t1 * d1 * u);
        }
      }
  }
}

// ---------------------------------------------------------------------------
// K4: per-sample grad/hdiag reduce + finalize (bf16 S1/C1, 8-wide loads)
// ---------------------------------------------------------------------------
__global__ __launch_bounds__(256) void k_grad_fin(
    const float* __restrict__ W1, const ushort* __restrict__ S1b,
    const ushort* __restrict__ C1b, const float* __restrict__ HD2P,
    const float* __restrict__ POT, float* __restrict__ OUT) {
  const int b = blockIdx.x, tid = threadIdx.x;
  __shared__ float gtmp[DD], htmp[DD];
  const int wid = tid >> 6, lane = tid & 63;
  const int j0 = lane * 8;   // 64 lanes x 8 = 512

  for (int i = wid; i < DD; i += 4) {
    float4 wa = *reinterpret_cast<const float4*>(&W1[i * HH + j0]);
    float4 wb = *reinterpret_cast<const float4*>(&W1[i * HH + j0 + 4]);
    u16x8 sv = *reinterpret_cast<const u16x8*>(&S1b[b * HH + j0]);
    u16x8 cv = *reinterpret_cast<const u16x8*>(&C1b[b * HH + j0]);
    float wv[8] = {wa.x, wa.y, wa.z, wa.w, wb.x, wb.y, wb.z, wb.w};
    float gp = 0.f, hp = 0.f;
#pragma unroll
    for (int e = 0; e < 8; ++e) {
      gp = fmaf(wv[e], bf2f(sv[e]), gp);
      hp = fmaf(wv[e] * wv[e], bf2f(cv[e]), hp);
    }
#pragma unroll
    for (int off = 32; off > 0; off >>= 1) {
      gp += __shfl_down(gp, off);
      hp += __shfl_down(hp, off);
    }
    if (lane == 0) { gtmp[i] = gp; htmp[i] = hp; }
  }
  __syncthreads();

  if (tid < 64) {
    float gv = 0.f, hv = 0.f;
    if (tid < DD) {
      gv = gtmp[tid];
      float h = htmp[tid];
#pragma unroll
      for (int c = 0; c < NCB; ++c) h += HD2P[c * ROWS + b * DD + tid];
      if (h >= -1e30f && h <= 1e30f) h = fminf(fmaxf(h, -50.f), 50.f);
      else h = 0.f;
      hv = h;
    }
    float sq = gv * gv;
#pragma unroll
    for (int off = 32; off > 0; off >>= 1) {
      sq += __shfl_down(sq, off);
      hv += __shfl_down(hv, off);
    }
    if (tid == 0) {
      float kin = fminf(fmaxf(-0.5f * (hv + sq), -100.f), 100.f);
      OUT[b] = kin + POT[b];
    }
  }
}

// ---------------------------------------------------------------------------
extern "C" void kernel_launch(void* const* d_in, const int* in_sizes, int n_in,
                              void* d_out, int out_size, void* d_ws, size_t ws_size,
                              hipStream_t stream) {
  const float* X    = (const float*)d_in[0];  // [1024,16,3]
  const float* ATOM = (const float*)d_in[1];  // [4,3]
  const float* Z    = (const float*)d_in[2];  // [4]
  const float* W1   = (const float*)d_in[3];  // [48,512]
  const float* B1   = (const float*)d_in[4];  // [512]
  const float* W2   = (const float*)d_in[5];  // [512,512]
  const float* B2   = (const float*)d_in[6];  // [512]
  const float* w3   = (const float*)d_in[7];  // [512]
  float* out = (float*)d_out;

  float* ws = (float*)d_ws;                         // offsets in float slots
  ushort* W2b  = (ushort*)ws;                       // 512*512 ush = 131072 fl
  ushort* W2Tb = (ushort*)(ws + 131072);            // 131072 fl
  ushort* T1b  = (ushort*)(ws + 262144);            // 1024*512 ush = 131072 fl
  ushort* Vb   = (ushort*)(ws + 393216);            // 131072 fl
  ushort* S1b  = (ushort*)(ws + 524288);            // 131072 fl
  ushort* C1b  = (ushort*)(ws + 655360);            // 131072 fl
  float*  D1   = ws + 786432;                       // 524288 fl
  float*  C2   = D1 + BTOT * HH;                    // 524288 fl
  float*  POT  = C2 + BTOT * HH;                    // 1024
  float*  HD2P = POT + BTOT;                        // 4*49152 = 196608
  ushort* Abig = (ushort*)(HD2P + NCB * ROWS);      // 49152*512 ush (~50 MB)

  k_l1pot<<<BTOT, 256, 0, stream>>>(X, ATOM, Z, W1, B1, W2, W2b, W2Tb,
                                    T1b, D1, Abig, POT);
  k_act64<<<128, 256, 0, stream>>>(T1b, W2Tb, B2, w3, C2, Vb);
  k_mu<<<MG + 128, 256, 0, stream>>>(Abig, W2Tb, C2, HD2P,
                                     Vb, W2b, D1, T1b, S1b, C1b);
  k_grad_fin<<<BTOT, 256, 0, stream>>>(W1, S1b, C1b, HD2P, POT, out);
}